// Round 5
// baseline (92006.232 us; speedup 1.0000x reference)
//
#include <hip/hip_runtime.h>

#define TT 2048
#define BB 512
#define II 5
#define HH 64
#define NTHR 768

__device__ __forceinline__ float sigm(float v)   { return 1.0f / (1.0f + __expf(-v)); }
__device__ __forceinline__ float tanh_f(float v) { return 1.0f - 2.0f / (1.0f + __expf(2.0f * v)); }

// One batch element per block; 3 groups x 256 threads, one weight row each.
// Live-set budget: allocator grants 512/6 = 85 VGPRs at 6 waves/EU (measured
// R4). Design peak ~80: w[16]=64 + 2x-b128 h transients (8) + ~8 misc.
__global__ __launch_bounds__(NTHR)
__attribute__((amdgpu_waves_per_eu(6, 6)))   // pin 2 blocks/CU, budget 85 VGPR
void lstm2_kernel(
    const float* __restrict__ x,
    const float* __restrict__ W_ih0, const float* __restrict__ W_hh0,
    const float* __restrict__ b_ih0, const float* __restrict__ b_hh0,
    const float* __restrict__ W_ih1, const float* __restrict__ W_hh1,
    const float* __restrict__ b_ih1, const float* __restrict__ b_hh1,
    const float* __restrict__ W_out, const float* __restrict__ b_out,
    float* __restrict__ out)
{
    const int t    = threadIdx.x;
    const int b    = blockIdx.x;
    const int g    = t >> 8;        // 0: Whh0 rows  1: Wih1 rows  2: Whh1 rows
    const int r    = t & 255;
    const int gate = r >> 6;        // 0=i 1=f 2=g 3=o  (g0 only)

    __shared__ __align__(16) float h1s[HH];
    __shared__ __align__(16) float h2s[HH];
    __shared__ __align__(16) float act0[256];    // layer-0 gates (activated)
    __shared__ __align__(16) float pB[256];      // Wih1 . h1 partial
    __shared__ __align__(16) float pC[256];      // Whh1 . h2 partial
    __shared__ float bias0s[256];
    __shared__ float bias1s[256];
    __shared__ float wih0T[II][256];             // W_ih0 transposed
    __shared__ float xst[2][8];                  // x[s] staging, double-buffered

    // ---- one 64-float weight row per thread (held in regs all 2048 steps) ----
    const float* Wrow = (g == 0) ? (W_hh0 + r * HH)
                       : (g == 1) ? (W_ih1 + r * HH)
                                  : (W_hh1 + r * HH);
    float4 w[16];
    #pragma unroll
    for (int k = 0; k < 16; ++k) w[k] = ((const float4*)Wrow)[k];

    if (t < 256) {
        bias0s[t] = b_ih0[t] + b_hh0[t];
        bias1s[t] = b_ih1[t] + b_hh1[t];
        #pragma unroll
        for (int k = 0; k < II; ++k) wih0T[k][t] = W_ih0[t * II + k];
    }
    if (t < HH) { h1s[t] = 0.0f; h2s[t] = 0.0f; }

    const float* xb = x + (size_t)b * II;        // x[(s*BB + b)*II + k]
    if (t < II) xst[0][t] = xb[t];               // stage x[0]

    float c = 0.0f;    // c1 on wave0 (t<64), c2 on wave1 (64<=t<128)
    __syncthreads();

    // Pipelined schedule (verified R3/R4): iter s computes gates0[s] (vs
    // h1[s-1]) and gates1[s-1] partials (vs h1[s-1], h2[s-2]); update phase
    // writes h1[s], h2[s-1]. Two barriers per step.
    for (int s = 0; s <= TT; ++s) {
        // issue next-step x load early (5 lanes of wave0); written to LDS late
        float xnv = 0.0f;
        if (t < II) {
            const int sn = (s + 1 < TT) ? (s + 1) : (TT - 1);
            xnv = xb[(size_t)sn * (BB * II) + t];
        }

        // ---- 64-FMA broadcast dot, 8 chunks of 2xb128 to cap h-transients ----
        const float4* hp = (g == 2) ? (const float4*)h2s : (const float4*)h1s;
        float acca = 0.0f, accb = 0.0f;
        #define DOT2(k0)                                                    \
        {                                                                   \
            float4 ha = hp[k0], hb = hp[k0 + 1];                            \
            acca = fmaf(ha.x, w[k0].x, acca);                               \
            acca = fmaf(ha.y, w[k0].y, acca);                               \
            acca = fmaf(ha.z, w[k0].z, acca);                               \
            acca = fmaf(ha.w, w[k0].w, acca);                               \
            accb = fmaf(hb.x, w[k0 + 1].x, accb);                           \
            accb = fmaf(hb.y, w[k0 + 1].y, accb);                           \
            accb = fmaf(hb.z, w[k0 + 1].z, accb);                           \
            accb = fmaf(hb.w, w[k0 + 1].w, accb);                           \
        }
        DOT2(0)  __builtin_amdgcn_sched_barrier(0);
        DOT2(2)  __builtin_amdgcn_sched_barrier(0);
        DOT2(4)  __builtin_amdgcn_sched_barrier(0);
        DOT2(6)  __builtin_amdgcn_sched_barrier(0);
        DOT2(8)  __builtin_amdgcn_sched_barrier(0);
        DOT2(10) __builtin_amdgcn_sched_barrier(0);
        DOT2(12) __builtin_amdgcn_sched_barrier(0);
        DOT2(14)
        #undef DOT2
        const float acc = acca + accb;

        // write staged x for next step (load issued above has drained by now)
        if (t < II) xst[(s + 1) & 1][t] = xnv;

        if (g == 0) {
            // xd = W_ih0[r,:] . x[s]   (x + W_ih0 both LDS-resident)
            const float* xs = xst[s & 1];
            float xd;
            xd = xs[0] * wih0T[0][r];
            xd = fmaf(xs[1], wih0T[1][r], xd);
            xd = fmaf(xs[2], wih0T[2][r], xd);
            xd = fmaf(xs[3], wih0T[3][r], xd);
            xd = fmaf(xs[4], wih0T[4][r], xd);
            const float pre = acc + xd + bias0s[r];
            act0[r] = (gate == 2) ? tanh_f(pre) : sigm(pre);
        } else if (g == 1) {
            pB[r] = acc;
        } else {
            pC[r] = acc;
        }
        __syncthreads();                         // A: act0/pB/pC ready

        if (t < 2 * HH) {
            const int l = t & 63;
            if (t < HH) {                        // wave0: layer-0 update -> h1[s]
                if (s < TT) {
                    float iv = act0[l], fv = act0[64 + l];
                    float gv = act0[128 + l], ov = act0[192 + l];
                    c = fmaf(fv, c, iv * gv);
                    h1s[l] = ov * tanh_f(c);
                }
            } else if (s >= 1) {                 // wave1: layer-1 update -> h2[s-1]
                float bi = pB[l]       + pC[l]       + bias1s[l];
                float bf = pB[64 + l]  + pC[64 + l]  + bias1s[64 + l];
                float bg = pB[128 + l] + pC[128 + l] + bias1s[128 + l];
                float bo = pB[192 + l] + pC[192 + l] + bias1s[192 + l];
                float iv = sigm(bi), fv = sigm(bf), gv = tanh_f(bg), ov = sigm(bo);
                c = fmaf(fv, c, iv * gv);
                h2s[l] = ov * tanh_f(c);
            }
        }
        __syncthreads();                         // B: h1s/h2s ready
    }

    // ---- final projection: out[b] = h2[TT-1] . W_out + b_out ----
    if (t < HH) {
        float v = h2s[t] * W_out[t];
        #pragma unroll
        for (int off = 32; off > 0; off >>= 1) v += __shfl_xor(v, off);
        if (t == 0) out[b] = v + b_out[0];
    }
}

extern "C" void kernel_launch(void* const* d_in, const int* in_sizes, int n_in,
                              void* d_out, int out_size, void* d_ws, size_t ws_size,
                              hipStream_t stream) {
    const float* x     = (const float*)d_in[0];
    const float* W_ih0 = (const float*)d_in[1];
    const float* W_hh0 = (const float*)d_in[2];
    const float* b_ih0 = (const float*)d_in[3];
    const float* b_hh0 = (const float*)d_in[4];
    const float* W_ih1 = (const float*)d_in[5];
    const float* W_hh1 = (const float*)d_in[6];
    const float* b_ih1 = (const float*)d_in[7];
    const float* b_hh1 = (const float*)d_in[8];
    const float* W_out = (const float*)d_in[9];
    const float* b_out = (const float*)d_in[10];
    float* out = (float*)d_out;

    lstm2_kernel<<<dim3(BB), dim3(NTHR), 0, stream>>>(
        x, W_ih0, W_hh0, b_ih0, b_hh0, W_ih1, W_hh1, b_ih1, b_hh1, W_out, b_out, out);
}

// Round 6
// 11218.309 us; speedup vs baseline: 8.2014x; 8.2014x over previous
//
#include <hip/hip_runtime.h>

#define TT 2048
#define BB 512
#define II 5

__device__ __forceinline__ float sigm(float v)   { return 1.0f / (1.0f + __expf(-v)); }
__device__ __forceinline__ float tanh_f(float v) { return 1.0f - 2.0f / (1.0f + __expf(2.0f * v)); }

__device__ __forceinline__ float dot4(float4 w, float4 h, float acc) {
    acc = fmaf(h.x, w.x, acc);
    acc = fmaf(h.y, w.y, acc);
    acc = fmaf(h.z, w.z, acc);
    acc = fmaf(h.w, w.w, acc);
    return acc;
}

// 1024 threads = 16 waves. Thread (q = t>>8, r = t&255) owns the 16-float
// chunk q of row r of W_hh0, W_ih1, W_hh1 (48 weight floats, 12 VGPR-quads).
// 2 batch elems per block, grid 256 -> exactly 1 block/CU, single pass.
// LDS is deliberately 84 KB: caps occupancy at 1 block/CU, so the compiler's
// own occupancy calc (16 waves = 4 waves/EU) yields a 128-VGPR budget and it
// allocates the ~100 live regs WITHOUT spilling (R1 precedent; R2/R3/R5
// proved attributes/KEEP only cause spills).
__global__ __launch_bounds__(1024) void lstm2_kernel(
    const float* __restrict__ x,
    const float* __restrict__ W_ih0, const float* __restrict__ W_hh0,
    const float* __restrict__ b_ih0, const float* __restrict__ b_hh0,
    const float* __restrict__ W_ih1, const float* __restrict__ W_hh1,
    const float* __restrict__ b_ih1, const float* __restrict__ b_hh1,
    const float* __restrict__ W_out, const float* __restrict__ b_out,
    float* __restrict__ out)
{
    const int t   = threadIdx.x;
    const int blk = blockIdx.x;           // batch elems 2*blk, 2*blk+1
    const int q   = t >> 8;               // chunk 0..3
    const int r   = t & 255;              // gate row 0..255

    __shared__ __align__(16) float big[21504];   // 84 KB (see note above)
    float* pA  = big;          // [2][4][256] layer-0 partials: e*1024+q*256+row
    float* pD  = big + 2048;   // [2][4][256] layer-1 partials
    float* h1s = big + 4096;   // [2][64]
    float* h2s = big + 4224;   // [2][64]
    float* xst = big + 4352;   // [2][16] staged x: buf*16 + e*8 + k

    // ---- per-thread weights (held in regs for all 2048 steps) ----
    float4 wA[4], wB[4], wC[4];
    {
        const float4* ap = (const float4*)(W_hh0 + r * 64 + q * 16);
        const float4* bp = (const float4*)(W_ih1 + r * 64 + q * 16);
        const float4* cp = (const float4*)(W_hh1 + r * 64 + q * 16);
        #pragma unroll
        for (int k = 0; k < 4; ++k) { wA[k] = ap[k]; wB[k] = bp[k]; wC[k] = cp[k]; }
    }
    float wih0[II], bias0 = 0.f, bias1 = 0.f;
    if (q == 0) {
        #pragma unroll
        for (int k = 0; k < II; ++k) wih0[k] = W_ih0[r * II + k];
        bias0 = b_ih0[r] + b_hh0[r];
        bias1 = b_ih1[r] + b_hh1[r];
    }

    if (t < 256) big[4096 + t] = 0.f;     // zero h1s, h2s
    if (t < 16) {                          // stage x[0] for both elems
        const int e = t >> 3, k = t & 7;
        xst[t] = (k < II) ? x[(size_t)(2 * blk + e) * II + k] : 0.f;
    }

    float c = 0.f;                         // cell state (update waves, t<256)
    const int uw_e     = (t >> 7) & 1;     // update wave -> elem
    const int uw_layer = (t >> 6) & 1;     // update wave -> layer
    const int ul       = t & 63;

    __syncthreads();

    // Pipelined schedule (R3/R4/R5-verified): iter s computes gates0[s]
    // (vs h1[s-1]) and gates1[s-1] (vs h1[s-1], h2[s-2]); update writes
    // h1[s], h2[s-1]. Two barriers per step.
    for (int s = 0; s <= TT; ++s) {
        // prefetch x[s+1] (issue early, LDS-write late)
        float xn = 0.f;
        if (t < 16) {
            const int sn = (s + 1 < TT) ? (s + 1) : (TT - 1);
            const int e = t >> 3, k = t & 7;
            if (k < II) xn = x[((size_t)sn * BB + 2 * blk + e) * II + k];
        }

        // ---- dot phase: elem 0 ----
        const float4* h1p0 = (const float4*)(h1s)      + q * 4;
        const float4* h2p0 = (const float4*)(h2s)      + q * 4;
        float accA0 = 0.f, accB0 = 0.f, accC0 = 0.f;
        #pragma unroll
        for (int k = 0; k < 4; ++k) {
            float4 hv = h1p0[k];                  // broadcast ds_read_b128
            accA0 = dot4(wA[k], hv, accA0);
            accB0 = dot4(wB[k], hv, accB0);
        }
        #pragma unroll
        for (int k = 0; k < 4; ++k) {
            float4 hv = h2p0[k];
            accC0 = dot4(wC[k], hv, accC0);
        }
        __builtin_amdgcn_sched_barrier(0);        // cap transient pressure
        // ---- dot phase: elem 1 ----
        const float4* h1p1 = (const float4*)(h1s + 64) + q * 4;
        const float4* h2p1 = (const float4*)(h2s + 64) + q * 4;
        float accA1 = 0.f, accB1 = 0.f, accC1 = 0.f;
        #pragma unroll
        for (int k = 0; k < 4; ++k) {
            float4 hv = h1p1[k];
            accA1 = dot4(wA[k], hv, accA1);
            accB1 = dot4(wB[k], hv, accB1);
        }
        #pragma unroll
        for (int k = 0; k < 4; ++k) {
            float4 hv = h2p1[k];
            accC1 = dot4(wC[k], hv, accC1);
        }

        float d0 = accB0 + accC0;
        float d1 = accB1 + accC1;
        if (q == 0) {                              // fold bias + x-dot
            const float* xs = xst + (s & 1) * 16;
            float xd0 = 0.f, xd1 = 0.f;
            #pragma unroll
            for (int k = 0; k < II; ++k) {
                xd0 = fmaf(xs[k],     wih0[k], xd0);
                xd1 = fmaf(xs[8 + k], wih0[k], xd1);
            }
            accA0 += bias0 + xd0;
            accA1 += bias0 + xd1;
            d0 += bias1;
            d1 += bias1;
        }
        pA[q * 256 + r]        = accA0;
        pA[1024 + q * 256 + r] = accA1;
        pD[q * 256 + r]        = d0;
        pD[1024 + q * 256 + r] = d1;

        if (t < 16) xst[((s + 1) & 1) * 16 + t] = xn;   // stage next x
        __syncthreads();                            // A: partials ready

        // ---- update phase: 4 waves, one per SIMD ----
        if (t < 256) {
            const bool go = uw_layer ? (s >= 1) : (s < TT);
            if (go) {
                const float* P = (uw_layer ? pD : pA) + uw_e * 1024;
                float pi = P[ul]       + P[256 + ul] + P[512 + ul] + P[768 + ul];
                float pf = P[64 + ul]  + P[320 + ul] + P[576 + ul] + P[832 + ul];
                float pg = P[128 + ul] + P[384 + ul] + P[640 + ul] + P[896 + ul];
                float po = P[192 + ul] + P[448 + ul] + P[704 + ul] + P[960 + ul];
                float iv = sigm(pi), fv = sigm(pf), gv = tanh_f(pg), ov = sigm(po);
                c = fmaf(fv, c, iv * gv);
                (uw_layer ? h2s : h1s)[uw_e * 64 + ul] = ov * tanh_f(c);
            }
        }
        __syncthreads();                            // B: h1s/h2s ready
    }

    // ---- final projection: out[2*blk+e] = h2[TT-1] . W_out + b_out ----
    if (t < 128) {
        const int e = t >> 6, l = t & 63;
        float v = h2s[e * 64 + l] * W_out[l];
        #pragma unroll
        for (int off = 32; off > 0; off >>= 1) v += __shfl_xor(v, off);
        if (l == 0) out[2 * blk + e] = v + b_out[0];
    }
}

extern "C" void kernel_launch(void* const* d_in, const int* in_sizes, int n_in,
                              void* d_out, int out_size, void* d_ws, size_t ws_size,
                              hipStream_t stream) {
    const float* x     = (const float*)d_in[0];
    const float* W_ih0 = (const float*)d_in[1];
    const float* W_hh0 = (const float*)d_in[2];
    const float* b_ih0 = (const float*)d_in[3];
    const float* b_hh0 = (const float*)d_in[4];
    const float* W_ih1 = (const float*)d_in[5];
    const float* W_hh1 = (const float*)d_in[6];
    const float* b_ih1 = (const float*)d_in[7];
    const float* b_hh1 = (const float*)d_in[8];
    const float* W_out = (const float*)d_in[9];
    const float* b_out = (const float*)d_in[10];
    float* out = (float*)d_out;

    lstm2_kernel<<<dim3(BB / 2), dim3(1024), 0, stream>>>(
        x, W_ih0, W_hh0, b_ih0, b_hh0, W_ih1, W_hh1, b_ih1, b_hh1, W_out, b_out, out);
}